// Round 12
// baseline (127.207 us; speedup 1.0000x reference)
//
#include <hip/hip_runtime.h>

// out[bg,d,h,w] = sum_c ref[bg,c,h,w]*tgt[bg,c,h,w-d]; B*G=16, Cg=64, H=128, W=256, D=48.
// Block = (bg, h-pair), full W. All HBM reads are 2KB contiguous runs (DRAM-row friendly).
#define HH 128
#define WW 256
#define ND 48
#define TPB 512
#define CCH 16            // channels per chunk (4 chunks)
#define RP 18             // shorts per (w,h) LDS row: 16 data + 2 pad (9 dwords)
#define OP 264            // outb pitch (floats)

typedef __attribute__((ext_vector_type(8))) short short8v;   // MFMA A/B frag
typedef __attribute__((ext_vector_type(4))) float float4v;   // MFMA C/D

__device__ __forceinline__ short f2bf(float x) {             // RNE f32->bf16
    unsigned u = __builtin_bit_cast(unsigned, x);
    u += 0x7fffu + ((u >> 16) & 1u);
    return (short)(u >> 16);
}

// Frag read: 4 dwords of row, dword m at column ((k0h+m)^S) (S wave-uniform).
__device__ __forceinline__ short8v ldfrag(const short* rowp, int S, int k0h) {
    union { int i[4]; short8v v; } u;
    #pragma unroll
    for (int m = 0; m < 4; ++m) u.i[m] = *(const int*)(rowp + 2 * ((k0h + m) ^ S));
    return u.v;
}

__global__ __launch_bounds__(TPB, 4)
void gwc_mfma(const float* __restrict__ ref, const float* __restrict__ tgt,
              float* __restrict__ out) {
    __shared__ __align__(16) char smem[50688];
    short* sref = (short*)smem;             // [w<256][h<2][RP]  = 18432 B
    short* stgt = (short*)(smem + 18432);   // [rt<304][h<2][RP] = 21888 B (rt = w'+48)
    float* outb = (float*)smem;             // [48][OP] overlays staging after MFMA

    const int tid  = threadIdx.x;
    const int lane = tid & 63;
    const int wv   = tid >> 6;       // 8 waves
    const int fr   = lane & 15;
    const int fhi  = lane >> 4;
    const int hw   = wv & 1;         // wave's h (0/1)
    const int ntg  = wv >> 1;        // n-tile group: NT = 4*ntg + n

    // XCD swizzle (1024 = 8*128, bijective)
    const int blk = ((blockIdx.x & 7) << 7) | (blockIdx.x >> 3);
    const int bg  = blk >> 6;
    const int h0  = (blk & 63) << 1;  // h-pair base

    // zero tgt pad rows rt<48 (both h): first 864 dwords of stgt
    for (int i = tid; i < 864; i += TPB) ((int*)stgt)[i] = 0;

    // staging coords (shared by ref and tgt): c=tid>>5, h=(tid>>4)&1, 16-float seg
    const int sc_ = tid >> 5;
    const int sh  = (tid >> 4) & 1;
    const int seg = tid & 15;
    const float* rptr0 = ref + ((size_t)(bg * 64 + sc_) * HH + (h0 + sh)) * WW + 16 * seg;
    const float* tptr0 = tgt + ((size_t)(bg * 64 + sc_) * HH + (h0 + sh)) * WW + 16 * seg;
    const size_t cstep = (size_t)CCH * HH * WW;
    // swizzled column short index (constant per thread)
    const int scr = 2 * ((sc_ >> 1) ^ (seg & 7) ^ (sh << 2)) + (sc_ & 1);
    const int sct = 2 * ((sc_ >> 1) ^ ((seg + 3) & 7) ^ (sh << 2)) + (sc_ & 1);

    float4v acc[4][4];
    #pragma unroll
    for (int n = 0; n < 4; ++n)
        #pragma unroll
        for (int t = 0; t < 4; ++t) acc[n][t] = (float4v){0.f, 0.f, 0.f, 0.f};

    for (int ch = 0; ch < 4; ++ch) {
        // ---- wide contiguous loads: thread reads 64B of ref + 64B of tgt;
        //      a wave covers 2 x 2KB contiguous runs per input ----
        float4 g0, g1, g2, g3, t0, t1, t2, t3;
        {
            const float* rp = rptr0 + ch * cstep;
            const float* tp = tptr0 + ch * cstep;
            g0 = *(const float4*)(rp + 0);  g1 = *(const float4*)(rp + 4);
            g2 = *(const float4*)(rp + 8);  g3 = *(const float4*)(rp + 12);
            t0 = *(const float4*)(tp + 0);  t1 = *(const float4*)(tp + 4);
            t2 = *(const float4*)(tp + 8);  t3 = *(const float4*)(tp + 12);
        }
        __syncthreads();   // WAR: prev chunk's frag reads done before overwrite
        // ---- transpose into LDS [w][h][c] as bf16 (swizzled columns) ----
#define WRT(J, V)                                                                  \
        {                                                                          \
            const int wbase = 16 * seg + 4 * J;                                    \
            sref[((wbase + 0) * 2 + sh) * RP + scr] = f2bf(V.x);                   \
            sref[((wbase + 1) * 2 + sh) * RP + scr] = f2bf(V.y);                   \
            sref[((wbase + 2) * 2 + sh) * RP + scr] = f2bf(V.z);                   \
            sref[((wbase + 3) * 2 + sh) * RP + scr] = f2bf(V.w);                   \
        }
#define WTT(J, V)                                                                  \
        {                                                                          \
            const int rbase = 16 * seg + 4 * J + 48;                               \
            stgt[((rbase + 0) * 2 + sh) * RP + sct] = f2bf(V.x);                   \
            stgt[((rbase + 1) * 2 + sh) * RP + sct] = f2bf(V.y);                   \
            stgt[((rbase + 2) * 2 + sh) * RP + sct] = f2bf(V.z);                   \
            stgt[((rbase + 3) * 2 + sh) * RP + sct] = f2bf(V.w);                   \
        }
        WRT(0, g0) WRT(1, g1) WRT(2, g2) WRT(3, g3)
        WTT(0, t0) WTT(1, t1) WTT(2, t2) WTT(3, t3)
#undef WRT
#undef WTT
        __syncthreads();
        // ---- frags + band MFMAs (k 0..15 real, k 16..31 zero) ----
        short8v bf[4], af[7];
        if (fhi < 2) {
            const int k0h = 4 * fhi;
            #pragma unroll
            for (int n = 0; n < 4; ++n) {
                const int NT = 4 * ntg + n;
                bf[n] = ldfrag(&sref[((16 * NT + fr) * 2 + hw) * RP],
                               (NT & 7) ^ (hw << 2), k0h);
            }
            #pragma unroll
            for (int m = 0; m < 7; ++m) {
                const int MT = 4 * ntg + m;
                af[m] = ldfrag(&stgt[((16 * MT + fr) * 2 + hw) * RP],
                               (MT & 7) ^ (hw << 2), k0h);
            }
        } else {
            #pragma unroll
            for (int n = 0; n < 4; ++n) bf[n] = (short8v){0,0,0,0,0,0,0,0};
            #pragma unroll
            for (int m = 0; m < 7; ++m) af[m] = (short8v){0,0,0,0,0,0,0,0};
        }
        #pragma unroll
        for (int n = 0; n < 4; ++n)
            #pragma unroll
            for (int t = 0; t < 4; ++t)
                acc[n][t] = __builtin_amdgcn_mfma_f32_16x16x32_bf16(
                                af[n + t], bf[n], acc[n][t], 0, 0, 0);
    }

    __syncthreads();   // staging dead; outb overlays it
    // ---- per-h phases: scatter diagonal d = 48-16t+fr-4fhi-rg, then 1KB stores ----
    #pragma unroll
    for (int ph = 0; ph < 2; ++ph) {
        if (hw == ph) {
            #pragma unroll
            for (int n = 0; n < 4; ++n) {
                const int wl = 16 * (4 * ntg + n) + fr;
                #pragma unroll
                for (int t = 0; t < 4; ++t)
                    #pragma unroll
                    for (int rg = 0; rg < 4; ++rg) {
                        const int d = 48 - 16 * t + fr - 4 * fhi - rg;
                        if ((unsigned)d < (unsigned)ND) outb[d * OP + wl] = acc[n][t][rg];
                    }
            }
        }
        __syncthreads();
        #pragma unroll
        for (int j = 0; j < 6; ++j) {
            const int idx = tid + 512 * j;          // < 3072 = 48d * 64 quads
            const int dd  = idx >> 6;
            const int wq  = idx & 63;
            *(float4*)(out + ((size_t)(bg * ND + dd) * HH + h0 + ph) * WW + 4 * wq) =
                *(const float4*)&outb[dd * OP + 4 * wq];
        }
        if (ph == 0) __syncthreads();   // store reads done before h=1 scatter
    }
}

extern "C" void kernel_launch(void* const* d_in, const int* in_sizes, int n_in,
                              void* d_out, int out_size, void* d_ws, size_t ws_size,
                              hipStream_t stream) {
    const float* ref = (const float*)d_in[0];
    const float* tgt = (const float*)d_in[1];
    float* out = (float*)d_out;
    gwc_mfma<<<dim3(16 * 64), dim3(TPB), 0, stream>>>(ref, tgt, out);
}

// Round 13
// 76.786 us; speedup vs baseline: 1.6567x; 1.6567x over previous
//
#include <hip/hip_runtime.h>

// out[bg,d,h,w] = sum_c ref[bg,c,h,w]*tgt[bg,c,h,w-d]; B*G=16, Cg=64, H=128, W=256, D=48.
// Block = (bg, h-pair), full W; 2KB-contiguous HBM reads; bf16 MFMA band-GEMM.
// r12 machinery (verified absmax 0.25) re-tiled spill-free: 16 waves, acc[2][4]/thread.
#define HH 128
#define WW 256
#define ND 48
#define TPB 1024
#define RP 18             // shorts per (w,h) LDS row: 16 data + 2 pad (9 dwords)
#define OP 264            // outb pitch (floats)

typedef __attribute__((ext_vector_type(8))) short short8v;   // MFMA A/B frag
typedef __attribute__((ext_vector_type(4))) float float4v;   // MFMA C/D

__device__ __forceinline__ short f2bf(float x) {             // RNE f32->bf16
    unsigned u = __builtin_bit_cast(unsigned, x);
    u += 0x7fffu + ((u >> 16) & 1u);
    return (short)(u >> 16);
}

// Frag read: 4 dwords of row, dword m at column ((k0h+m)^S); S,k0h+m in [0,8).
__device__ __forceinline__ short8v ldfrag(const short* rowp, int S, int k0h) {
    union { int i[4]; short8v v; } u;
    #pragma unroll
    for (int m = 0; m < 4; ++m) u.i[m] = *(const int*)(rowp + 2 * ((k0h + m) ^ S));
    return u.v;
}

__global__ __launch_bounds__(TPB, 4)
void gwc_mfma(const float* __restrict__ ref, const float* __restrict__ tgt,
              float* __restrict__ out) {
    __shared__ __align__(16) char smem[50688];
    short* sref = (short*)smem;             // [w<256][h<2][RP]  = 18432 B
    short* stgt = (short*)(smem + 18432);   // [rt<304][h<2][RP] = 21888 B (rt = w'+48)
    float* outb = (float*)smem;             // [48][OP] overlays staging after MFMA

    const int tid  = threadIdx.x;
    const int lane = tid & 63;
    const int wv   = tid >> 6;       // 16 waves
    const int fr   = lane & 15;
    const int fhi  = lane >> 4;
    const int hw   = wv & 1;         // wave's h (0/1)
    const int ntg  = wv >> 1;        // 0..7: n-tiles NT = 2*ntg + {0,1}

    // XCD swizzle (1024 = 8*128, bijective)
    const int blk = ((blockIdx.x & 7) << 7) | (blockIdx.x >> 3);
    const int bg  = blk >> 6;
    const int h0  = (blk & 63) << 1;  // h-pair base

    // zero tgt pad rows rt<48 (both h): first 864 dwords of stgt (written once)
    if (tid < 864) ((int*)stgt)[tid] = 0;

    // ---- staging coords: half-block 0 stages ref, half-block 1 stages tgt ----
    // u = tid&511: c = u>>5 (16 channels/chunk), h = (u>>4)&1, seg = u&15 (16 floats).
    // A wave covers 2 channels x 2KB contiguous per load batch.
    const int ht  = tid >> 9;
    const int u   = tid & 511;
    const int sc_ = u >> 5;
    const int sh  = (u >> 4) & 1;
    const int seg = u & 15;
    const float* gbase = (ht ? tgt : ref)
        + ((size_t)(bg * 64 + sc_) * HH + (h0 + sh)) * WW + 16 * seg;
    const size_t cstep = (size_t)16 * HH * WW;
    // swizzled dword column (constant/thread); row base for this thread's 16 w's
    const int scol = 2 * ((sc_ >> 1) ^ ((ht ? (seg + 3) : seg) & 7) ^ (sh << 2)) + (sc_ & 1);
    short* sdst = ht ? &stgt[((48 + 16 * seg) * 2 + sh) * RP + scol]
                     : &sref[((16 * seg) * 2 + sh) * RP + scol];

    float4v acc[2][4];
    #pragma unroll
    for (int n = 0; n < 2; ++n)
        #pragma unroll
        for (int t = 0; t < 4; ++t) acc[n][t] = (float4v){0.f, 0.f, 0.f, 0.f};

    for (int ch = 0; ch < 4; ++ch) {
        // ---- wide contiguous loads: 64B/thread from one input ----
        const float* gp = gbase + ch * cstep;
        const float4 f0 = *(const float4*)(gp + 0);
        const float4 f1 = *(const float4*)(gp + 4);
        const float4 f2 = *(const float4*)(gp + 8);
        const float4 f3 = *(const float4*)(gp + 12);
        __syncthreads();   // WAR: prev chunk's frag reads done before overwrite
        // ---- transpose into LDS [w][h][c] bf16 (swizzled columns) ----
#define PUT(J, V)                                                              \
        {                                                                      \
            short* p = sdst + (8 * J) * RP;   /* w advances by 4J: 4*2*RP */   \
            p[0 * RP] = f2bf(V.x);                                             \
            p[2 * RP] = f2bf(V.y);                                             \
            p[4 * RP] = f2bf(V.z);                                             \
            p[6 * RP] = f2bf(V.w);                                             \
        }
        PUT(0, f0) PUT(1, f1) PUT(2, f2) PUT(3, f3)
#undef PUT
        __syncthreads();
        // ---- frags + band MFMAs (k 0..15 real, k 16..31 zero via fhi>=2 zeros) ----
        short8v bf[2], af[5];
        if (fhi < 2) {
            const int k0h = 4 * fhi;
            #pragma unroll
            for (int n = 0; n < 2; ++n) {
                const int NT = 2 * ntg + n;
                bf[n] = ldfrag(&sref[((16 * NT + fr) * 2 + hw) * RP],
                               (NT & 7) ^ (hw << 2), k0h);
            }
            #pragma unroll
            for (int m = 0; m < 5; ++m) {
                const int MT = 2 * ntg + m;
                af[m] = ldfrag(&stgt[((16 * MT + fr) * 2 + hw) * RP],
                               (MT & 7) ^ (hw << 2), k0h);
            }
        } else {
            #pragma unroll
            for (int n = 0; n < 2; ++n) bf[n] = (short8v){0,0,0,0,0,0,0,0};
            #pragma unroll
            for (int m = 0; m < 5; ++m) af[m] = (short8v){0,0,0,0,0,0,0,0};
        }
        #pragma unroll
        for (int n = 0; n < 2; ++n)
            #pragma unroll
            for (int t = 0; t < 4; ++t)
                acc[n][t] = __builtin_amdgcn_mfma_f32_16x16x32_bf16(
                                af[n + t], bf[n], acc[n][t], 0, 0, 0);
    }

    __syncthreads();   // staging dead; outb overlays it
    // ---- per-h phases: scatter diagonal d = 48-16t+fr-4fhi-rg, then 2KB stores ----
    #pragma unroll
    for (int ph = 0; ph < 2; ++ph) {
        if (hw == ph) {
            #pragma unroll
            for (int n = 0; n < 2; ++n) {
                const int wl = 16 * (2 * ntg + n) + fr;
                #pragma unroll
                for (int t = 0; t < 4; ++t)
                    #pragma unroll
                    for (int rg = 0; rg < 4; ++rg) {
                        const int d = 48 - 16 * t + fr - 4 * fhi - rg;
                        if ((unsigned)d < (unsigned)ND) outb[d * OP + wl] = acc[n][t][rg];
                    }
            }
        }
        __syncthreads();
        #pragma unroll
        for (int j = 0; j < 3; ++j) {
            const int idx = tid + TPB * j;          // < 3072 = 48d * 64 quads
            const int dd  = idx >> 6;
            const int wq  = idx & 63;
            const float4v v = *(const float4v*)&outb[dd * OP + 4 * wq];
            __builtin_nontemporal_store(
                v, (float4v*)(out + ((size_t)(bg * ND + dd) * HH + h0 + ph) * WW + 4 * wq));
        }
        if (ph == 0) __syncthreads();   // store reads done before h=1 scatter
    }
}

extern "C" void kernel_launch(void* const* d_in, const int* in_sizes, int n_in,
                              void* d_out, int out_size, void* d_ws, size_t ws_size,
                              hipStream_t stream) {
    const float* ref = (const float*)d_in[0];
    const float* tgt = (const float*)d_in[1];
    float* out = (float*)d_out;
    gwc_mfma<<<dim3(16 * 64), dim3(TPB), 0, stream>>>(ref, tgt, out);
}